// Round 1
// baseline (117.635 us; speedup 1.0000x reference)
//
#include <hip/hip_runtime.h>

#define IN_F   512
#define OUT_F  512
#define GRID_N 8
#define BATCH  4096
#define KDIM   (IN_F * 9)        // 4608
#define SPLITK 4
#define KCHUNK (KDIM / SPLITK)   // 1152
#define BKSTEPS (KCHUNK / 32)    // 36

typedef __fp16 half8 __attribute__((ext_vector_type(8)));
typedef float  f32x4 __attribute__((ext_vector_type(4)));

__device__ __forceinline__ void gload16(const void* gsrc, void* ldst) {
  __builtin_amdgcn_global_load_lds(
      (__attribute__((address_space(1))) void*)(void*)gsrc,
      (__attribute__((address_space(3))) void*)ldst, 16, 0, 0);
}

// ---------------- feature expansion: Phi[b][g*512+i] -----------------------
__global__ void feat_kernel(const float* __restrict__ x, const float* __restrict__ grid,
                            __fp16* __restrict__ A) {
  const int idx = blockIdx.x * 256 + threadIdx.x;   // b*512 + i, 0..2M-1
  const float xn = tanhf(x[idx]);
  const int b = idx >> 9;
  const int i = idx & (IN_F - 1);
  __fp16* arow = A + (size_t)b * KDIM + i;
#pragma unroll
  for (int g = 0; g < GRID_N; ++g) {
    const float d  = fabsf(xn - grid[g]);
    const float dd = d * d;
    const float inner = 1.0f - 6.0f * dd + 6.0f * dd * d;
    const float om = 1.0f - d;
    const float outer = 2.0f * om * om * om;
    const float bas = (d < 0.5f) ? inner : ((d < 1.0f) ? outer : 0.0f);
    arow[g * IN_F] = (__fp16)bas;
  }
  arow[8 * IN_F] = (__fp16)xn;
}

// ---------------- weight pack: Wp[o][g*512+i] ------------------------------
__global__ void wt_kernel(const float* __restrict__ sw, const float* __restrict__ ba,
                          __fp16* __restrict__ W) {
  const int idx = blockIdx.x * 256 + threadIdx.x;   // o*512 + i
  const int o = idx >> 9;
  const int i = idx & (IN_F - 1);
  const float* swp = sw + (size_t)idx * GRID_N;     // spline_weight[o][i][*]
  __fp16* wrow = W + (size_t)o * KDIM + i;
#pragma unroll
  for (int g = 0; g < GRID_N; ++g) wrow[g * IN_F] = (__fp16)swp[g];
  wrow[8 * IN_F] = (__fp16)(0.1f * ba[idx]);
}

// ---------------- split-K GEMM: P[kc][m][n] = Phi_chunk . Wp_chunk^T -------
__global__ __launch_bounds__(256) void gemm_kernel(const __fp16* __restrict__ A,
                                                   const __fp16* __restrict__ W,
                                                   float* __restrict__ P) {
  __shared__ __align__(16) __fp16 As[128 * 32];
  __shared__ __align__(16) __fp16 Bs[128 * 32];
  const int tid  = threadIdx.x;
  const int lane = tid & 63;
  const int wv   = tid >> 6;       // wave 0..3
  const int wm   = wv >> 1;        // wave row 0..1
  const int wn   = wv & 1;         // wave col 0..1
  const int m0 = blockIdx.x * 128;
  const int n0 = blockIdx.y * 128;
  const int kbase = blockIdx.z * KCHUNK;

  // staging: tile is 128 rows x 32 halves (64B/row), 8192B. wave wv covers
  // bytes [wv*1024, +1024) and [4096+wv*1024, +1024); lane adds l*16.
  const int e0 = wv * 512 + lane * 8;           // half index within tile, issue 0
  const int r0 = e0 >> 5, c0 = e0 & 31;
  const int r1 = (e0 + 2048) >> 5, c1 = (e0 + 2048) & 31;
  const __fp16* Ag0 = A + (size_t)(m0 + r0) * KDIM + kbase + c0;
  const __fp16* Ag1 = A + (size_t)(m0 + r1) * KDIM + kbase + c1;
  const __fp16* Wg0 = W + (size_t)(n0 + r0) * KDIM + kbase + c0;
  const __fp16* Wg1 = W + (size_t)(n0 + r1) * KDIM + kbase + c1;
  __fp16* lA0 = &As[wv * 512];          // wave-uniform LDS bases
  __fp16* lA1 = &As[wv * 512 + 2048];
  __fp16* lB0 = &Bs[wv * 512];
  __fp16* lB1 = &Bs[wv * 512 + 2048];

  const int fr = lane & 15;
  const int g4 = lane >> 4;

  f32x4 acc[4][4] = {};

  for (int kt = 0; kt < BKSTEPS; ++kt) {
    gload16(Ag0, lA0);
    gload16(Ag1, lA1);
    gload16(Wg0, lB0);
    gload16(Wg1, lB1);
    Ag0 += 32; Ag1 += 32; Wg0 += 32; Wg1 += 32;
    __syncthreads();                      // compiler drains vmcnt before barrier
    half8 a[4], b[4];
#pragma unroll
    for (int mi = 0; mi < 4; ++mi)
      a[mi] = *(const half8*)&As[(wm * 64 + mi * 16 + fr) * 32 + g4 * 8];
#pragma unroll
    for (int ni = 0; ni < 4; ++ni)
      b[ni] = *(const half8*)&Bs[(wn * 64 + ni * 16 + fr) * 32 + g4 * 8];
#pragma unroll
    for (int mi = 0; mi < 4; ++mi)
#pragma unroll
      for (int ni = 0; ni < 4; ++ni)
        acc[mi][ni] = __builtin_amdgcn_mfma_f32_16x16x32_f16(a[mi], b[ni], acc[mi][ni], 0, 0, 0);
    __syncthreads();
  }

  float* Pp = P + (size_t)blockIdx.z * (BATCH * OUT_F);
#pragma unroll
  for (int mi = 0; mi < 4; ++mi) {
#pragma unroll
    for (int ni = 0; ni < 4; ++ni) {
      const int row = m0 + wm * 64 + mi * 16 + g4 * 4;   // C/D: row=(lane>>4)*4+reg
      const int col = n0 + wn * 64 + ni * 16 + fr;       //      col=lane&15
#pragma unroll
      for (int rg = 0; rg < 4; ++rg)
        Pp[(size_t)(row + rg) * OUT_F + col] = acc[mi][ni][rg];
    }
  }
}

// ---------------- reduce 4 split-K partials --------------------------------
__global__ void reduce_kernel(const float* __restrict__ P, float* __restrict__ out) {
  const int idx = blockIdx.x * 256 + threadIdx.x;   // f32x4 index, 0..524287
  const f32x4* P4 = (const f32x4*)P;
  const int stride = (BATCH * OUT_F) / 4;           // 524288
  f32x4 s = P4[idx] + P4[idx + stride] + P4[idx + 2 * stride] + P4[idx + 3 * stride];
  ((f32x4*)out)[idx] = s;
}

extern "C" void kernel_launch(void* const* d_in, const int* in_sizes, int n_in,
                              void* d_out, int out_size, void* d_ws, size_t ws_size,
                              hipStream_t stream) {
  const float* x  = (const float*)d_in[0];
  const float* sw = (const float*)d_in[1];
  const float* ba = (const float*)d_in[2];
  const float* gp = (const float*)d_in[3];
  float* out = (float*)d_out;

  char* ws = (char*)d_ws;
  const size_t A_BYTES = (size_t)BATCH * KDIM * 2;   // 37,748,736
  const size_t W_BYTES = (size_t)OUT_F * KDIM * 2;   //  4,718,592
  __fp16* A = (__fp16*)ws;
  __fp16* W = (__fp16*)(ws + A_BYTES);
  float*  P = (float*)(ws + A_BYTES + W_BYTES);      // 32 MB of f32 partials

  feat_kernel<<<(BATCH * IN_F) / 256, 256, 0, stream>>>(x, gp, A);
  wt_kernel<<<(OUT_F * IN_F) / 256, 256, 0, stream>>>(sw, ba, W);
  gemm_kernel<<<dim3(BATCH / 128, OUT_F / 128, SPLITK), 256, 0, stream>>>(A, W, P);
  reduce_kernel<<<(BATCH * OUT_F) / 4 / 256, 256, 0, stream>>>(P, out);
}

// Round 2
// 109.429 us; speedup vs baseline: 1.0750x; 1.0750x over previous
//
#include <hip/hip_runtime.h>

#define IN_F   512
#define OUT_F  512
#define GRID_N 8
#define BATCH  4096
#define KDIM   (IN_F * 9)        // 4608
#define SPLITK 4
#define KCHUNK (KDIM / SPLITK)   // 1152
#define BK     64
#define BKSTEPS (KCHUNK / BK)    // 18

typedef __fp16 half8 __attribute__((ext_vector_type(8)));
typedef float  f32x4 __attribute__((ext_vector_type(4)));

__device__ __forceinline__ void gload16(const void* gsrc, void* ldst) {
  __builtin_amdgcn_global_load_lds(
      (__attribute__((address_space(1))) void*)(void*)gsrc,
      (__attribute__((address_space(3))) void*)ldst, 16, 0, 0);
}

// ------- prep: feature expansion Phi[b][g*512+i] + weight pack -------------
__global__ void prep_kernel(const float* __restrict__ x, const float* __restrict__ grid,
                            const float* __restrict__ sw, const float* __restrict__ ba,
                            __fp16* __restrict__ A, __fp16* __restrict__ W) {
  const int bid = blockIdx.x;
  if (bid < (BATCH * IN_F) / 256) {            // ---- feat path ----
    const int idx = bid * 256 + threadIdx.x;   // b*512 + i
    const float xn = tanhf(x[idx]);
    const int b = idx >> 9;
    const int i = idx & (IN_F - 1);
    __fp16* arow = A + (size_t)b * KDIM + i;
#pragma unroll
    for (int g = 0; g < GRID_N; ++g) {
      const float d  = fabsf(xn - grid[g]);
      const float dd = d * d;
      const float inner = 1.0f - 6.0f * dd + 6.0f * dd * d;
      const float om = 1.0f - d;
      const float outer = 2.0f * om * om * om;
      const float bas = (d < 0.5f) ? inner : ((d < 1.0f) ? outer : 0.0f);
      arow[g * IN_F] = (__fp16)bas;
    }
    arow[8 * IN_F] = (__fp16)xn;
  } else {                                     // ---- weight path ----
    const int idx = (bid - (BATCH * IN_F) / 256) * 256 + threadIdx.x;  // o*512+i
    const float* swp = sw + (size_t)idx * GRID_N;
    __fp16* wrow = W + (size_t)(idx >> 9) * KDIM + (idx & (IN_F - 1));
#pragma unroll
    for (int g = 0; g < GRID_N; ++g) wrow[g * IN_F] = (__fp16)swp[g];
    wrow[8 * IN_F] = (__fp16)(0.1f * ba[idx]);
  }
}

// ------- split-K GEMM: P[z][m][n] = Phi_chunk . Wp_chunk^T -----------------
// LDS tile 128 rows x 64 halves (128B row). XOR swizzle: 16B chunk index
// within a row is chunk ^ (row&7); applied on the pre-swizzled GLOBAL source
// (LDS dest stays linear for global_load_lds) and identically on ds_read.
__global__ __launch_bounds__(256) void gemm_kernel(const __fp16* __restrict__ A,
                                                   const __fp16* __restrict__ W,
                                                   float* __restrict__ P) {
  __shared__ __align__(16) __fp16 As[128 * BK];
  __shared__ __align__(16) __fp16 Bs[128 * BK];
  const int tid  = threadIdx.x;
  const int lane = tid & 63;
  const int wv   = tid >> 6;
  const int wm   = wv >> 1;
  const int wn   = wv & 1;
  const int m0 = blockIdx.x * 128;
  const int n0 = blockIdx.y * 128;
  const int kbase = blockIdx.z * KCHUNK;

  // staging: issue t = wv*4+j covers halves [t*512, +512): rows t*8 + lane/8,
  // lds cols (lane&7)*8; global col chunk pre-swizzled by ^(row&7).
  const __fp16* Ag[4];
  const __fp16* Wg[4];
  __fp16* lA[4];
  __fp16* lB[4];
#pragma unroll
  for (int j = 0; j < 4; ++j) {
    const int t = wv * 4 + j;
    const int r = t * 8 + (lane >> 3);
    const int cs = (((lane & 7) ^ (r & 7))) * 8;
    Ag[j] = A + (size_t)(m0 + r) * KDIM + kbase + cs;
    Wg[j] = W + (size_t)(n0 + r) * KDIM + kbase + cs;
    lA[j] = &As[t * 512];
    lB[j] = &Bs[t * 512];
  }

  const int fr = lane & 15;
  const int g4 = lane >> 4;
  const int xr = fr & 7;               // read-side row-XOR (row&7 == fr&7)

  f32x4 acc[4][4] = {};

  for (int kt = 0; kt < BKSTEPS; ++kt) {
#pragma unroll
    for (int j = 0; j < 4; ++j) {
      gload16(Ag[j], lA[j]);
      gload16(Wg[j], lB[j]);
      Ag[j] += BK; Wg[j] += BK;
    }
    __syncthreads();                   // drains vmcnt: tile resident

    half8 a[2][4], b[2][4];
#pragma unroll
    for (int ks = 0; ks < 2; ++ks) {
#pragma unroll
      for (int mi = 0; mi < 4; ++mi) {
        const int row = wm * 64 + mi * 16 + fr;
        const int ch = (ks * 4 + g4) ^ xr;
        a[ks][mi] = *(const half8*)&As[row * BK + ch * 8];
      }
#pragma unroll
      for (int ni = 0; ni < 4; ++ni) {
        const int row = wn * 64 + ni * 16 + fr;
        const int ch = (ks * 4 + g4) ^ xr;
        b[ks][ni] = *(const half8*)&Bs[row * BK + ch * 8];
      }
    }
#pragma unroll
    for (int ks = 0; ks < 2; ++ks)
#pragma unroll
      for (int mi = 0; mi < 4; ++mi)
#pragma unroll
        for (int ni = 0; ni < 4; ++ni)
          acc[mi][ni] = __builtin_amdgcn_mfma_f32_16x16x32_f16(a[ks][mi], b[ks][ni], acc[mi][ni], 0, 0, 0);
    __syncthreads();
  }

  float* Pp = P + (size_t)blockIdx.z * (BATCH * OUT_F);
#pragma unroll
  for (int mi = 0; mi < 4; ++mi) {
#pragma unroll
    for (int ni = 0; ni < 4; ++ni) {
      const int row = m0 + wm * 64 + mi * 16 + g4 * 4;   // C/D: row=(lane>>4)*4+reg
      const int col = n0 + wn * 64 + ni * 16 + fr;       //      col=lane&15
#pragma unroll
      for (int rg = 0; rg < 4; ++rg)
        Pp[(size_t)(row + rg) * OUT_F + col] = acc[mi][ni][rg];
    }
  }
}

// ------- reduce 4 split-K partials -----------------------------------------
__global__ void reduce_kernel(const float* __restrict__ P, float* __restrict__ out) {
  const int idx = blockIdx.x * 256 + threadIdx.x;
  const f32x4* P4 = (const f32x4*)P;
  const int stride = (BATCH * OUT_F) / 4;
  f32x4 s = P4[idx] + P4[idx + stride] + P4[idx + 2 * stride] + P4[idx + 3 * stride];
  ((f32x4*)out)[idx] = s;
}

extern "C" void kernel_launch(void* const* d_in, const int* in_sizes, int n_in,
                              void* d_out, int out_size, void* d_ws, size_t ws_size,
                              hipStream_t stream) {
  const float* x  = (const float*)d_in[0];
  const float* sw = (const float*)d_in[1];
  const float* ba = (const float*)d_in[2];
  const float* gp = (const float*)d_in[3];
  float* out = (float*)d_out;

  char* ws = (char*)d_ws;
  const size_t A_BYTES = (size_t)BATCH * KDIM * 2;   // 37,748,736
  const size_t W_BYTES = (size_t)OUT_F * KDIM * 2;   //  4,718,592
  __fp16* A = (__fp16*)ws;
  __fp16* W = (__fp16*)(ws + A_BYTES);
  float*  P = (float*)(ws + A_BYTES + W_BYTES);      // 32 MB f32 partials

  const int FEAT_BLKS = (BATCH * IN_F) / 256;        // 8192
  const int WT_BLKS   = (OUT_F * IN_F) / 256;        // 1024
  prep_kernel<<<FEAT_BLKS + WT_BLKS, 256, 0, stream>>>(x, gp, sw, ba, A, W);
  gemm_kernel<<<dim3(BATCH / 128, OUT_F / 128, SPLITK), 256, 0, stream>>>(A, W, P);
  reduce_kernel<<<(BATCH * OUT_F) / 4 / 256, 256, 0, stream>>>(P, out);
}